// Round 1
// baseline (418.274 us; speedup 1.0000x reference)
//
#include <hip/hip_runtime.h>
#include <hip/hip_bf16.h>

// B=16, M=4096, D=64, K=1024. fp32 in / fp32 out.
// Output: [z_q_st (N*D) | indices (N) | loss (1)], fp32.
//
// R13 post-mortem: LDS-instruction bound. 16.8M ds_read_b128 x 12cyc/instr
// /256CU/2.4GHz = 328us ~= measured 357us. FMA floor is only 55us.
// R14: amortize each broadcast LDS code read over R=4 rows per thread
// (xv[4][64] = 256 VGPR, launch_bounds(TPB,1) -> 1 wave/SIMD, 4 waves/CU).
// ds_read_b128 count /4 -> 4.2M -> ~82us LDS floor; FMA 60us/SIMD under it.
// TPB=128 (128 rows/block, 512 blocks = 2 blocks/CU for barrier overlap),
// TK=256 (half the barriers, 71KB LDS, 2 blocks still fit in 160KB).
// Exactness: fp32 screen, merged top-2 gap < MARGIN -> wave-cooperative
// exact fp64 rescan (R12-proven code path, unchanged semantics).
#define D_     64
#define K_     1024
#define N_     65536
#define TK     256            // codes per LDS tile
#define STRIDE 68             // padded floats per code (68%32=4 -> bank shift)
#define TPB    128            // 32 quads x 4 threads
#define R_     4              // rows per thread
#define RPB    (TPB / 4 * R_) // 128 rows per block
#define NBLK   (N_ / RPB)     // 512 blocks
#define MARGIN 1.0e-2f        // fp32 screen err ~1e-4 worst case; 100x safety

// ---------------------------------------------------------------------------
// Kernel A: ||e_k||^2 exact fp64 + fp32 copy for the screen
// ---------------------------------------------------------------------------
__global__ __launch_bounds__(256) void vq_norms(const float* __restrict__ embed,
                                                double* __restrict__ n64,
                                                float* __restrict__ n32) {
    const int k = blockIdx.x * 256 + threadIdx.x;
    const float4* e4 = (const float4*)(embed + (size_t)k * D_);
    double acc = 0.0;
#pragma unroll
    for (int q = 0; q < 16; ++q) {
        const float4 e = e4[q];
        acc = fma((double)e.x, (double)e.x, acc);
        acc = fma((double)e.y, (double)e.y, acc);
        acc = fma((double)e.z, (double)e.z, acc);
        acc = fma((double)e.w, (double)e.w, acc);
    }
    n64[k] = acc;
    n32[k] = (float)acc;
}

// ---------------------------------------------------------------------------
// Kernel B: quad = 4 threads over 4 shared rows; each thread scans its
// parity's K/4 codes against all 4 rows (one LDS read feeds 4 rows of FMA).
// fp32 screen over padded LDS tiles; quad top-2 merge; cooperative exact
// fp64 rescan for near-ties; split epilogue.
// ---------------------------------------------------------------------------
__global__ __launch_bounds__(TPB, 1) void vq_main(const float* __restrict__ z_e,
                                                  const float* __restrict__ embed,
                                                  const float* __restrict__ n32,
                                                  const double* __restrict__ n64,
                                                  float* __restrict__ out,
                                                  float* __restrict__ partials) {
    __shared__ float lds_e[TK * STRIDE];   // 68 KB padded code tile
    __shared__ float lds_n[TK];
    __shared__ float red[TPB];

    const int tid  = threadIdx.x;
    const int p    = tid & 3;              // parity: which k mod 4 this lane scans
    const int qd   = tid >> 2;             // quad index within block
    const int row0 = blockIdx.x * RPB + qd * R_;
    const int lane = tid & 63;

    // R_ rows of z_e -> registers (all 4 quad lanes hold the same 4 rows)
    float xv[R_][D_];
#pragma unroll
    for (int r = 0; r < R_; ++r) {
        const float4* xg = (const float4*)(z_e + (size_t)(row0 + r) * D_);
#pragma unroll
        for (int q = 0; q < 16; ++q) {
            const float4 x = xg[q];
            xv[r][q * 4 + 0] = x.x; xv[r][q * 4 + 1] = x.y;
            xv[r][q * 4 + 2] = x.z; xv[r][q * 4 + 3] = x.w;
        }
    }

    float b1[R_], b2[R_];
    int   i1[R_];
#pragma unroll
    for (int r = 0; r < R_; ++r) { b1[r] = 3.4e38f; b2[r] = 3.4e38f; i1[r] = 0; }

    for (int kt = 0; kt < K_; kt += TK) {
        __syncthreads();
        {   // stage TK codes into padded LDS: 4096 float4, 32 per thread
            const float4* esrc = (const float4*)(embed + (size_t)kt * D_);
#pragma unroll
            for (int i = 0; i < (TK * D_ / 4) / TPB; ++i) {
                const int fidx = tid + i * TPB;        // float4 index in tile
                const int c = fidx >> 4, q = fidx & 15;
                *(float4*)(lds_e + c * STRIDE + q * 4) = esrc[fidx];
            }
#pragma unroll
            for (int i = tid; i < TK; i += TPB) lds_n[i] = n32[kt + i];
        }
        __syncthreads();

        // Lane scans codes kt+p, kt+p+4, ... (ascending within parity).
        // Quad's 4 concurrent addresses differ by 68 words -> bank shift 4 ->
        // disjoint bank quartets; 16-lane same-address broadcast is free.
        // Each 16-float4 code read is amortized over R_=4 rows (256 FMAs).
#pragma unroll 2
        for (int j = 0; j < TK / 4; ++j) {
            const int kl = 4 * j + p;
            const float4* ev = (const float4*)(lds_e + kl * STRIDE);
            float acc[R_][4];
#pragma unroll
            for (int r = 0; r < R_; ++r) {
                acc[r][0] = 0.f; acc[r][1] = 0.f;
                acc[r][2] = 0.f; acc[r][3] = 0.f;
            }
#pragma unroll
            for (int q = 0; q < 16; ++q) {
                const float4 e = ev[q];
#pragma unroll
                for (int r = 0; r < R_; ++r) {
                    acc[r][0] = fmaf(xv[r][q * 4 + 0], e.x, acc[r][0]);
                    acc[r][1] = fmaf(xv[r][q * 4 + 1], e.y, acc[r][1]);
                    acc[r][2] = fmaf(xv[r][q * 4 + 2], e.z, acc[r][2]);
                    acc[r][3] = fmaf(xv[r][q * 4 + 3], e.w, acc[r][3]);
                }
            }
            const int   ki = kt + kl;
            const float nk = lds_n[kl];
#pragma unroll
            for (int r = 0; r < R_; ++r) {
                const float s = fmaf(-2.0f,
                                     (acc[r][0] + acc[r][1]) + (acc[r][2] + acc[r][3]),
                                     nk);
                if (s < b1[r])      { b2[r] = b1[r]; b1[r] = s; i1[r] = ki; }
                else if (s < b2[r]) { b2[r] = s; }
            }
        }
    }

    // Merge quad top-2 per row (lex (score,idx) => first-minimum preserved).
#pragma unroll
    for (int r = 0; r < R_; ++r) {
#pragma unroll
        for (int off = 1; off <= 2; off <<= 1) {
            const float ob1 = __shfl_xor(b1[r], off);
            const float ob2 = __shfl_xor(b2[r], off);
            const int   oi1 = __shfl_xor(i1[r], off);
            if (ob1 < b1[r] || (ob1 == b1[r] && oi1 < i1[r])) {
                b2[r] = fminf(b1[r], ob2); b1[r] = ob1; i1[r] = oi1;
            } else {
                b2[r] = fminf(ob1, b2[r]);
            }
        }
    }

    // Near-tie rows: wave-cooperative EXACT fp64 full-K rescan (rare).
#pragma unroll
    for (int r = 0; r < R_; ++r) {
        unsigned long long mask = __ballot((p == 0) && (b2[r] - b1[r] < MARGIN));
        while (mask) {
            const int src = __ffsll((long long)mask) - 1;
            mask &= mask - 1;
            double bs = 1.0e300; int bi = 1 << 30;
            for (int c0 = 0; c0 < K_; c0 += 64) {
                const int c = c0 + lane;
                const float* ep = embed + (size_t)c * D_;
                double dot = 0.0;
#pragma unroll
                for (int jj = 0; jj < D_; ++jj) {
                    const float xj = __shfl(xv[r][jj], src);   // broadcast row x
                    dot = fma((double)xj, (double)ep[jj], dot);
                }
                const double s = fma(-2.0, dot, n64[c]);
                if (s < bs) { bs = s; bi = c; }
            }
#pragma unroll
            for (int off = 32; off > 0; off >>= 1) {        // (s,idx) lex-min
                const double so = __shfl_xor(bs, off);
                const int    io = __shfl_xor(bi, off);
                if (so < bs || (so == bs && io < bi)) { bs = so; bi = io; }
            }
            if (lane == src) i1[r] = bi;
        }
    }

    // Broadcast final indices from quad leader; clamp for safe gather.
    int bidx[R_];
#pragma unroll
    for (int r = 0; r < R_; ++r) bidx[r] = __shfl(i1[r], lane & ~3) & (K_ - 1);

    // Split epilogue: lane m of the quad handles 16 of each row's 64 floats.
    float sq = 0.f;
#pragma unroll
    for (int r = 0; r < R_; ++r) {
        const float4* eg = (const float4*)(embed + (size_t)bidx[r] * D_) + p * 4;
        float4*       o0 = (float4*)(out + (size_t)(row0 + r) * D_) + p * 4;
#pragma unroll
        for (int q = 0; q < 4; ++q) {
            const float4 e = eg[q];
            const int   x0 = p * 16 + q * 4;
            const float d0 = e.x - xv[r][x0 + 0];
            const float d1 = e.y - xv[r][x0 + 1];
            const float d2 = e.z - xv[r][x0 + 2];
            const float d3 = e.w - xv[r][x0 + 3];
            sq = fmaf(d0, d0, sq); sq = fmaf(d1, d1, sq);
            sq = fmaf(d2, d2, sq); sq = fmaf(d3, d3, sq);
            float4 o;
            o.x = xv[r][x0 + 0] + d0;
            o.y = xv[r][x0 + 1] + d1;
            o.z = xv[r][x0 + 2] + d2;
            o.w = xv[r][x0 + 3] + d3;
            o0[q] = o;
        }
        if (p == 0) out[(size_t)N_ * D_ + row0 + r] = (float)bidx[r];
    }

    // Block loss reduction (each element counted exactly once)
    red[tid] = sq;
    __syncthreads();
#pragma unroll
    for (int s = TPB / 2; s > 0; s >>= 1) {
        if (tid < s) red[tid] += red[tid + s];
        __syncthreads();
    }
    if (tid == 0) partials[blockIdx.x] = red[0];
}

// ---------------------------------------------------------------------------
// Kernel C: reduce NBLK partials -> vq_loss = 1.25 * mean(sqdiff), fp32
// ---------------------------------------------------------------------------
__global__ __launch_bounds__(256) void vq_loss_final(const float* __restrict__ partials,
                                                     float* __restrict__ out) {
    __shared__ float red[256];
    const int tid = threadIdx.x;
    float s = 0.f;
#pragma unroll
    for (int i = 0; i < NBLK / 256; ++i) s += partials[tid + i * 256];
    red[tid] = s;
    __syncthreads();
#pragma unroll
    for (int w = 128; w > 0; w >>= 1) {
        if (tid < w) red[tid] += red[tid + w];
        __syncthreads();
    }
    if (tid == 0)
        out[(size_t)N_ * D_ + N_] = 1.25f * red[0] / (float)((size_t)N_ * D_);
}

// ---------------------------------------------------------------------------
extern "C" void kernel_launch(void* const* d_in, const int* in_sizes, int n_in,
                              void* d_out, int out_size, void* d_ws, size_t ws_size,
                              hipStream_t stream) {
    const float* z_e;
    const float* embed;
    if (in_sizes[0] == N_ * D_) {
        z_e   = (const float*)d_in[0];
        embed = (const float*)d_in[1];
    } else {
        z_e   = (const float*)d_in[1];
        embed = (const float*)d_in[0];
    }
    float* out = (float*)d_out;

    double* n64      = (double*)d_ws;       // 8 KB
    float*  n32      = (float*)(n64 + K_);  // 4 KB
    float*  partials = n32 + K_;            // 2 KB

    vq_norms<<<K_ / 256, 256, 0, stream>>>(embed, n64, n32);
    vq_main<<<NBLK, TPB, 0, stream>>>(z_e, embed, n32, n64, out, partials);
    vq_loss_final<<<1, 256, 0, stream>>>(partials, out);
}

// Round 2
// 218.043 us; speedup vs baseline: 1.9183x; 1.9183x over previous
//
#include <hip/hip_runtime.h>
#include <hip/hip_bf16.h>
#include <stdint.h>

// B=16, M=4096, D=64, K=1024. fp32 in / fp32 out.
// Output: [z_q_st (N*D) | indices (N) | loss (1)], fp32.
//
// R14 post-mortem: xv[4][64] blew the 256-VGPR architectural cap -> scratch
// spill (WRITE +40MB, VALUBusy 38%, occupancy halved). VALU path is boxed:
// best non-spilling variant (R=2) has a ~165us LDS floor.
// R15: bf16 hi/lo split-GEMM screen on MFMA (hh+hl+lh, err <= ~1.4e-2,
// MARGIN=0.06 -> 2x the 2*eps criterion), exact fp64 rescan unchanged.
// Wave = 32 rows (2 rowtiles x 16) so each B-frag LDS read feeds 2 row-tiles.
// k-map kappa(l,s,i)=(l>>4)*16+s*8+i applied to BOTH A and B frags -> dot
// invariant to the HW's internal k wiring; only row/col = lane&15 and
// C/D row=(l>>4)*4+reg (m89/m91-verified) are load-bearing.
// LDS code tile XOR-swizzled (byte ^= (row&7)<<4): stride-128B rows would be
// a 16-way bank conflict on ds_read_b128 otherwise.
#define D_     64
#define K_     1024
#define N_     65536
#define TK     256            // codes per LDS tile
#define TPB    256            // 4 waves
#define RPW    32             // rows per wave (2 rowtiles of 16)
#define RPB    128            // rows per block
#define NBLK   (N_ / RPB)     // 512 blocks
#define MARGIN 0.06f          // screen err bound ~1.4e-2; need >= 2x

typedef __bf16 bf16x8 __attribute__((ext_vector_type(8)));
typedef float  f32x4  __attribute__((ext_vector_type(4)));

__device__ __forceinline__ unsigned short bf16_rne(float f) {
    union { float f; uint32_t u; } v; v.f = f;
    const uint32_t u = v.u;
    return (unsigned short)((u + 0x7fffu + ((u >> 16) & 1u)) >> 16);
}
__device__ __forceinline__ float bf16_tof(unsigned short h) {
    union { uint32_t u; float f; } v; v.u = ((uint32_t)h) << 16;
    return v.f;
}
__device__ __forceinline__ __bf16 bits_bf16(unsigned short u) {
    union { unsigned short u; __bf16 h; } v; v.u = u; return v.h;
}

// ---------------------------------------------------------------------------
// Kernel A: per-code exact fp64 norm (+fp32 copy) and bf16 hi/lo codebook
// ---------------------------------------------------------------------------
__global__ __launch_bounds__(256) void vq_prep(const float* __restrict__ embed,
                                               double* __restrict__ n64,
                                               float* __restrict__ n32,
                                               unsigned short* __restrict__ ehg,
                                               unsigned short* __restrict__ elg) {
    const int k = blockIdx.x * 256 + threadIdx.x;
    const float4* e4 = (const float4*)(embed + (size_t)k * D_);
    double acc = 0.0;
#pragma unroll
    for (int q = 0; q < 16; ++q) {
        const float4 e = e4[q];
        float c[4] = {e.x, e.y, e.z, e.w};
        ushort4 h4, l4;
        unsigned short hb[4], lb[4];
#pragma unroll
        for (int j = 0; j < 4; ++j) {
            hb[j] = bf16_rne(c[j]);
            lb[j] = bf16_rne(c[j] - bf16_tof(hb[j]));
            acc = fma((double)c[j], (double)c[j], acc);
        }
        h4.x = hb[0]; h4.y = hb[1]; h4.z = hb[2]; h4.w = hb[3];
        l4.x = lb[0]; l4.y = lb[1]; l4.z = lb[2]; l4.w = lb[3];
        *(ushort4*)(ehg + (size_t)k * D_ + q * 4) = h4;
        *(ushort4*)(elg + (size_t)k * D_ + q * 4) = l4;
    }
    n64[k] = acc;
    n32[k] = (float)acc;
}

// ---------------------------------------------------------------------------
// Kernel B: MFMA screen + fused per-row top-2 + exact fp64 rescan + epilogue
// ---------------------------------------------------------------------------
__global__ __launch_bounds__(TPB, 2) void vq_main(const float* __restrict__ z_e,
                                                  const float* __restrict__ embed,
                                                  const unsigned short* __restrict__ ehg,
                                                  const unsigned short* __restrict__ elg,
                                                  const float* __restrict__ n32g,
                                                  const double* __restrict__ n64g,
                                                  float* __restrict__ out,
                                                  float* __restrict__ partials) {
    __shared__ float4 lds_eh[TK * 8];   // 32 KB swizzled bf16 hi tile
    __shared__ float4 lds_el[TK * 8];   // 32 KB swizzled bf16 lo tile
    __shared__ float  lds_n[TK];
    __shared__ float  red[TPB];

    const int tid  = threadIdx.x;
    const int lane = tid & 63;
    const int w    = tid >> 6;          // wave id 0..3
    const int lg   = lane >> 4;         // k-chunk / row-group 0..3
    const int lc   = lane & 15;         // A-row within tile / code within subtile
    const int wrow0 = blockIdx.x * RPB + w * RPW;

    // ---- x rows (2 rowtiles): fp32 slice + bf16 hi/lo A-fragments ----
    float  xs[2][16];
    bf16x8 ah[2][2], al[2][2];
#pragma unroll
    for (int t = 0; t < 2; ++t) {
        const int row = wrow0 + t * 16 + lc;
        const float4* xg = (const float4*)(z_e + (size_t)row * D_ + lg * 16);
#pragma unroll
        for (int q = 0; q < 4; ++q) {
            const float4 x = xg[q];
            xs[t][q * 4 + 0] = x.x; xs[t][q * 4 + 1] = x.y;
            xs[t][q * 4 + 2] = x.z; xs[t][q * 4 + 3] = x.w;
        }
#pragma unroll
        for (int s = 0; s < 2; ++s) {
#pragma unroll
            for (int i = 0; i < 8; ++i) {
                const float xf = xs[t][s * 8 + i];
                const unsigned short hb = bf16_rne(xf);
                const unsigned short lb = bf16_rne(xf - bf16_tof(hb));
                ah[t][s][i] = bits_bf16(hb);
                al[t][s][i] = bits_bf16(lb);
            }
        }
    }

    float b1[2][4], b2[2][4];
    int   i1[2][4];
#pragma unroll
    for (int t = 0; t < 2; ++t)
#pragma unroll
        for (int rg = 0; rg < 4; ++rg) { b1[t][rg] = 3.4e38f; b2[t][rg] = 3.4e38f; i1[t][rg] = 0; }

    for (int kt = 0; kt < K_; kt += TK) {
        __syncthreads();
        {   // stage bf16 tiles, XOR-swizzled: LDS byte s holds logical byte
            // s ^ (((s>>7)&7)<<4). Writes: consecutive lanes -> consecutive
            // 16B within a row-octave -> conflict-free.
            const float4* sh = (const float4*)(ehg + (size_t)kt * D_);
            const float4* sl = (const float4*)(elg + (size_t)kt * D_);
#pragma unroll
            for (int it = 0; it < 8; ++it) {
                const int m  = tid + it * TPB;                 // float4 chunk id
                const int sw = (m * 16) ^ ((((m * 16) >> 7) & 7) << 4);
                lds_eh[sw >> 4] = sh[m];
                lds_el[sw >> 4] = sl[m];
            }
            lds_n[tid] = n32g[kt + tid];
        }
        __syncthreads();

#pragma unroll 4
        for (int ct = 0; ct < TK / 16; ++ct) {
            const int cl = ct * 16 + lc;                       // tile-local code
            const int a0 = (cl * 128 + lg * 32) ^ ((cl & 7) << 4);
            const bf16x8 bh0 = *(const bf16x8*)((const char*)lds_eh + a0);
            const bf16x8 bh1 = *(const bf16x8*)((const char*)lds_eh + (a0 ^ 16));
            const bf16x8 bl0 = *(const bf16x8*)((const char*)lds_el + a0);
            const bf16x8 bl1 = *(const bf16x8*)((const char*)lds_el + (a0 ^ 16));
            const float  nv  = lds_n[cl];
            const int    ki  = kt + cl;
#pragma unroll
            for (int t = 0; t < 2; ++t) {
                f32x4 acc = {0.f, 0.f, 0.f, 0.f};
                acc = __builtin_amdgcn_mfma_f32_16x16x32_bf16(ah[t][0], bh0, acc, 0, 0, 0);
                acc = __builtin_amdgcn_mfma_f32_16x16x32_bf16(ah[t][1], bh1, acc, 0, 0, 0);
                acc = __builtin_amdgcn_mfma_f32_16x16x32_bf16(ah[t][0], bl0, acc, 0, 0, 0);
                acc = __builtin_amdgcn_mfma_f32_16x16x32_bf16(ah[t][1], bl1, acc, 0, 0, 0);
                acc = __builtin_amdgcn_mfma_f32_16x16x32_bf16(al[t][0], bh0, acc, 0, 0, 0);
                acc = __builtin_amdgcn_mfma_f32_16x16x32_bf16(al[t][1], bh1, acc, 0, 0, 0);
#pragma unroll
                for (int rg = 0; rg < 4; ++rg) {
                    // score for row (lg*4+rg of rowtile t), code ki
                    const float s = fmaf(-2.0f, acc[rg], nv);
                    if (s < b1[t][rg])      { b2[t][rg] = b1[t][rg]; b1[t][rg] = s; i1[t][rg] = ki; }
                    else if (s < b2[t][rg]) { b2[t][rg] = s; }
                }
            }
        }
    }

    // Merge top-2 across the 16 lanes sharing rows (lex (score,idx)).
#pragma unroll
    for (int t = 0; t < 2; ++t)
#pragma unroll
        for (int rg = 0; rg < 4; ++rg)
#pragma unroll
            for (int off = 1; off <= 8; off <<= 1) {
                const float ob1 = __shfl_xor(b1[t][rg], off);
                const float ob2 = __shfl_xor(b2[t][rg], off);
                const int   oi1 = __shfl_xor(i1[t][rg], off);
                if (ob1 < b1[t][rg] || (ob1 == b1[t][rg] && oi1 < i1[t][rg])) {
                    b2[t][rg] = fminf(b1[t][rg], ob2); b1[t][rg] = ob1; i1[t][rg] = oi1;
                } else {
                    b2[t][rg] = fminf(ob1, b2[t][rg]);
                }
            }

    // Near-tie rows: wave-cooperative EXACT fp64 full-K rescan (rare).
#pragma unroll
    for (int t = 0; t < 2; ++t) {
#pragma unroll
        for (int rg = 0; rg < 4; ++rg) {
            for (int g = 0; g < 4; ++g) {          // runtime loop, uniform
                const float g1 = __shfl(b1[t][rg], g << 4);
                const float g2 = __shfl(b2[t][rg], g << 4);
                if (g2 - g1 < MARGIN) {
                    const int grow = wrow0 + t * 16 + g * 4 + rg;
                    const float* xp = z_e + (size_t)grow * D_;
                    double bs = 1.0e300; int bi = 1 << 30;
                    for (int c0 = 0; c0 < K_; c0 += 64) {
                        const int c = c0 + lane;
                        const float* ep = embed + (size_t)c * D_;
                        double dot = 0.0;
#pragma unroll
                        for (int j = 0; j < D_; ++j)
                            dot = fma((double)xp[j], (double)ep[j], dot);
                        const double sc = fma(-2.0, dot, n64g[c]);
                        if (sc < bs) { bs = sc; bi = c; }
                    }
#pragma unroll
                    for (int off = 32; off > 0; off >>= 1) {   // (s,idx) lex-min
                        const double so = __shfl_xor(bs, off);
                        const int    io = __shfl_xor(bi, off);
                        if (so < bs || (so == bs && io < bi)) { bs = so; bi = io; }
                    }
                    if (lg == g) i1[t][rg] = bi;
                }
            }
        }
    }

    // Epilogue: lane owns rows (t, lc), k-chunk lg*16..+16.
    float sq = 0.f;
#pragma unroll
    for (int t = 0; t < 2; ++t) {
        const int srcl = (lc >> 2) << 4;   // lane 0 of the group owning row lc
        const int c0v = __shfl(i1[t][0], srcl);
        const int c1v = __shfl(i1[t][1], srcl);
        const int c2v = __shfl(i1[t][2], srcl);
        const int c3v = __shfl(i1[t][3], srcl);
        const int rsel = lc & 3;
        int bidx = (rsel == 0) ? c0v : (rsel == 1) ? c1v : (rsel == 2) ? c2v : c3v;
        bidx &= (K_ - 1);
        const int row = wrow0 + t * 16 + lc;
        const float4* eg = (const float4*)(embed + (size_t)bidx * D_ + lg * 16);
        float4*       og = (float4*)(out + (size_t)row * D_ + lg * 16);
#pragma unroll
        for (int q = 0; q < 4; ++q) {
            const float4 e = eg[q];
            const int   x0 = q * 4;
            const float d0 = e.x - xs[t][x0 + 0];
            const float d1 = e.y - xs[t][x0 + 1];
            const float d2 = e.z - xs[t][x0 + 2];
            const float d3 = e.w - xs[t][x0 + 3];
            sq = fmaf(d0, d0, sq); sq = fmaf(d1, d1, sq);
            sq = fmaf(d2, d2, sq); sq = fmaf(d3, d3, sq);
            float4 o;                      // x + (e - x): match reference fp32 rounding
            o.x = xs[t][x0 + 0] + d0;
            o.y = xs[t][x0 + 1] + d1;
            o.z = xs[t][x0 + 2] + d2;
            o.w = xs[t][x0 + 3] + d3;
            og[q] = o;
        }
        if (lg == 0) out[(size_t)N_ * D_ + row] = (float)bidx;
    }

    // Block loss reduction (each element counted exactly once)
    red[tid] = sq;
    __syncthreads();
#pragma unroll
    for (int s = TPB / 2; s > 0; s >>= 1) {
        if (tid < s) red[tid] += red[tid + s];
        __syncthreads();
    }
    if (tid == 0) partials[blockIdx.x] = red[0];
}

// ---------------------------------------------------------------------------
// Kernel C: reduce NBLK partials -> vq_loss = 1.25 * mean(sqdiff), fp32
// ---------------------------------------------------------------------------
__global__ __launch_bounds__(256) void vq_loss_final(const float* __restrict__ partials,
                                                     float* __restrict__ out) {
    __shared__ float red[256];
    const int tid = threadIdx.x;
    float s = 0.f;
#pragma unroll
    for (int i = 0; i < NBLK / 256; ++i) s += partials[tid + i * 256];
    red[tid] = s;
    __syncthreads();
#pragma unroll
    for (int w = 128; w > 0; w >>= 1) {
        if (tid < w) red[tid] += red[tid + w];
        __syncthreads();
    }
    if (tid == 0)
        out[(size_t)N_ * D_ + N_] = 1.25f * red[0] / (float)((size_t)N_ * D_);
}

// ---------------------------------------------------------------------------
extern "C" void kernel_launch(void* const* d_in, const int* in_sizes, int n_in,
                              void* d_out, int out_size, void* d_ws, size_t ws_size,
                              hipStream_t stream) {
    const float* z_e;
    const float* embed;
    if (in_sizes[0] == N_ * D_) {
        z_e   = (const float*)d_in[0];
        embed = (const float*)d_in[1];
    } else {
        z_e   = (const float*)d_in[1];
        embed = (const float*)d_in[0];
    }
    float* out = (float*)d_out;

    double* n64           = (double*)d_ws;            // 8 KB
    float*  n32           = (float*)(n64 + K_);       // 4 KB
    float*  partials      = n32 + K_;                 // 2 KB
    unsigned short* ehg   = (unsigned short*)(partials + NBLK);  // 128 KB
    unsigned short* elg   = ehg + (size_t)K_ * D_;               // 128 KB

    vq_prep<<<K_ / 256, 256, 0, stream>>>(embed, n64, n32, ehg, elg);
    vq_main<<<NBLK, TPB, 0, stream>>>(z_e, embed, ehg, elg, n32, n64, out, partials);
    vq_loss_final<<<1, 256, 0, stream>>>(partials, out);
}